// Round 4
// baseline (551.747 us; speedup 1.0000x reference)
//
#include <hip/hip_runtime.h>

#define NBINS  16
#define TPB    256
#define BLOCKS 1024
#define DEPTH  4           // staging pipeline depth (power of 2)
#define DUMMY  16          // dead-slot redirect row (17th plane row, never read)
#define MAGIC  12582912.0f // 1.5 * 2^23: float->int round-to-nearest-even trick

// R3 -> R4: raw asm global_load into VGPR buffers NaN'd (allocator may copy an
// in-flight dest register). Safe equivalent with the SAME goal (more bytes in
// flight per wave): __builtin_amdgcn_global_load_lds staging, depth-4 rotating
// wave-private LDS slots, counted s_waitcnt vmcnt(6) in-loop (never 0), no
// barriers (each wave reads only its own slice). Theory: R0-R2's invariant
// 160us = concurrency limit (2KB in flight/wave behind compiler vmcnt(0) =>
// ~3.36 TB/s served). Depth-4 staging -> 8KB/wave in flight.
// LDS: 34.8KB hist + 32KB staging = 67KB -> 2 blocks/CU (8 waves/CU).

typedef unsigned long long u64;

__device__ __forceinline__ void gload_lds16(const void* g, void* l)
{
    // async DMA: lane i's 16B at g -> (wave-uniform l) + i*16; counts in vmcnt
    __builtin_amdgcn_global_load_lds(
        (const __attribute__((address_space(1))) unsigned int*)g,
        (__attribute__((address_space(3))) unsigned int*)l, 16, 0, 0);
}

__global__ __launch_bounds__(TPB, 2) void binreg_main(
    const float* __restrict__ w, const float* __restrict__ wq,
    const float* __restrict__ alpha_p, const int* __restrict__ nbit_p,
    float* __restrict__ partial, long long n)
{
    __shared__ float2 sv_pl[(NBINS + 1) * TPB];   // {sum,sumsq}, +dummy, 34.8 KB
    __shared__ float4 stgW[DEPTH][TPB];           // 16 KB staging, w
    __shared__ float4 stgQ[DEPTH][TPB];           // 16 KB staging, wq
    __shared__ float  cred[NBINS][TPB / 64];
    __shared__ float  sqpart[TPB / 64];

    const int tid    = threadIdx.x;
    const int wvbase = tid & ~63;                 // wave-uniform slice base

    #pragma unroll
    for (int k = 0; k < NBINS; ++k)
        sv_pl[k * TPB + tid] = make_float2(0.0f, 0.0f);
    // hist columns are thread-private until the epilogue fold; no barrier

    const float inv_a = 1.0f / alpha_p[0];
    const int   qoff  = 1 << (nbit_p[0] - 1);     // -Qn = 8 for nbit=4

    const long long n4     = n >> 2;
    const long long stride = (long long)BLOCKS * TPB;
    const float4* w4 = (const float4*)w;
    const float4* q4 = (const float4*)wq;

    float sq = 0.0f;
    u64 clo = 0ull, chi = 0ull;                   // 16 x 8-bit packed counters
    float cf[NBINS];
    #pragma unroll
    for (int k = 0; k < NBINS; ++k) cf[k] = 0.0f;

    #define FLUSH_COUNTS() do {                                   \
        _Pragma("unroll")                                         \
        for (int kk_ = 0; kk_ < 8; ++kk_) {                       \
            cf[kk_]     += (float)((clo >> (kk_ * 8)) & 0xffull); \
            cf[kk_ + 8] += (float)((chi >> (kk_ * 8)) & 0xffull); \
        }                                                         \
        clo = 0ull; chi = 0ull;                                   \
    } while (0)

    // one float4-pair worth of work; mutates sq/clo/chi/sv_pl  (R1/R2-verified)
    auto process = [&](float4 a, float4 b) {
        float d0 = b.x - a.x, d1 = b.y - a.y, d2 = b.z - a.z, d3 = b.w - a.w;
        sq += d0 * d0 + d1 * d1 + d2 * d2 + d3 * d3;

        const int b0 = (__float_as_int(fmaf(b.x, inv_a, MAGIC)) + qoff) & (NBINS - 1);
        const int b1 = (__float_as_int(fmaf(b.y, inv_a, MAGIC)) + qoff) & (NBINS - 1);
        const int b2 = (__float_as_int(fmaf(b.z, inv_a, MAGIC)) + qoff) & (NBINS - 1);
        const int b3 = (__float_as_int(fmaf(b.w, inv_a, MAGIC)) + qoff) & (NBINS - 1);

        {   // packed register counts (exact)
            u64 t;
            t = 1ull << ((b0 & 7) << 3); clo += (b0 < 8) ? t : 0ull; chi += (b0 < 8) ? 0ull : t;
            t = 1ull << ((b1 & 7) << 3); clo += (b1 < 8) ? t : 0ull; chi += (b1 < 8) ? 0ull : t;
            t = 1ull << ((b2 & 7) << 3); clo += (b2 < 8) ? t : 0ull; chi += (b2 < 8) ? 0ull : t;
            t = 1ull << ((b3 & 7) << 3); clo += (b3 < 8) ? t : 0ull; chi += (b3 < 8) ? 0ull : t;
        }

        // dedup: merge duplicate bins into the first (live) slot
        const bool e10 = (b1 == b0);
        const bool e20 = (b2 == b0);
        const bool e21 = (b2 == b1) && !e20;
        const bool e30 = (b3 == b0);
        const bool e31 = (b3 == b1) && !e30;
        const bool e32 = (b3 == b2) && !e30 && !e31;

        float sx0 = a.x, sx1 = a.y, sx2 = a.z, sx3 = a.w;
        float qx0 = a.x * a.x, qx1 = a.y * a.y, qx2 = a.z * a.z, qx3 = a.w * a.w;

        sx0 += e10 ? sx1 : 0.0f;  qx0 += e10 ? qx1 : 0.0f;
        sx0 += e20 ? sx2 : 0.0f;  qx0 += e20 ? qx2 : 0.0f;
        sx1 += e21 ? sx2 : 0.0f;  qx1 += e21 ? qx2 : 0.0f;
        sx0 += e30 ? sx3 : 0.0f;  qx0 += e30 ? qx3 : 0.0f;
        sx1 += e31 ? sx3 : 0.0f;  qx1 += e31 ? qx3 : 0.0f;
        sx2 += e32 ? sx3 : 0.0f;  qx2 += e32 ? qx3 : 0.0f;

        const int r1 = e10               ? DUMMY : b1;
        const int r2 = (e20 | e21)       ? DUMMY : b2;
        const int r3 = (e30 | e31 | e32) ? DUMMY : b3;
        const int a0 = (b0 << 8) + tid;
        const int a1 = (r1 << 8) + tid;
        const int a2 = (r2 << 8) + tid;
        const int a3 = (r3 << 8) + tid;

        // batched reads (distinct live addresses) -> ONE lgkmcnt wait
        float2 t0 = sv_pl[a0];
        float2 t1 = sv_pl[a1];
        float2 t2 = sv_pl[a2];
        float2 t3 = sv_pl[a3];
        t0.x += sx0; t0.y += qx0;
        t1.x += sx1; t1.y += qx1;
        t2.x += sx2; t2.y += qx2;
        t3.x += sx3; t3.y += qx3;
        sv_pl[a0] = t0;
        sv_pl[a1] = t1;
        sv_pl[a2] = t2;
        sv_pl[a3] = t3;
    };

    const long long start = (long long)blockIdx.x * TPB + tid;
    const long long tail_begin = n4 << 2;

    const bool uniform = (n4 > 0) && (n4 % stride == 0);
    const int  C       = uniform ? (int)(n4 / stride) : 0;   // trips, all threads

    if (uniform && C >= DEPTH) {
        // -------- fast path: depth-4 global_load_lds pipeline, counted vmcnt
        const float4* pw = w4 + start;       // per-lane global src
        const float4* pq = q4 + start;

        #define ISSUE(J) do {                                              \
            gload_lds16(pw + (long long)(J) * stride,                      \
                        &stgW[(J) & (DEPTH - 1)][wvbase]);                 \
            gload_lds16(pq + (long long)(J) * stride,                      \
                        &stgQ[(J) & (DEPTH - 1)][wvbase]);                 \
        } while (0)

        ISSUE(0); ISSUE(1); ISSUE(2);        // 6 loads outstanding

        int pend = 0;
        #pragma unroll 1
        for (int k = 0; k + DEPTH <= C; ++k) {
            ISSUE(k + 3);                                   // outstanding -> 8
            asm volatile("s_waitcnt vmcnt(6)" ::: "memory"); // stage k landed
            float4 a = stgW[k & (DEPTH - 1)][tid];
            float4 b = stgQ[k & (DEPTH - 1)][tid];
            process(a, b);
            // <=4 increments/field/iter; flush every 32 -> <=128 < 255
            if (++pend >= 32) { FLUSH_COUNTS(); pend = 0; }
        }
        FLUSH_COUNTS();
        {   // epilogue: drain stages C-3..C-1 with decreasing counts
            int k = C - 3;
            asm volatile("s_waitcnt vmcnt(4)" ::: "memory");
            process(stgW[k & (DEPTH - 1)][tid], stgQ[k & (DEPTH - 1)][tid]); ++k;
            asm volatile("s_waitcnt vmcnt(2)" ::: "memory");
            process(stgW[k & (DEPTH - 1)][tid], stgQ[k & (DEPTH - 1)][tid]); ++k;
            asm volatile("s_waitcnt vmcnt(0)" ::: "memory");
            process(stgW[k & (DEPTH - 1)][tid], stgQ[k & (DEPTH - 1)][tid]);
        }
        #undef ISSUE
    } else if (n4 > 0) {
        // -------- general fallback (any n): simple strided float4 loop
        int pend = 0;
        for (long long i = start; i < n4; i += stride) {
            process(w4[i], q4[i]);
            if (++pend >= 32) { FLUSH_COUNTS(); pend = 0; }
        }
    }

    // scalar tail (n divisible by 4 in practice; safety only)
    for (long long t = tail_begin + start; t < n; t += stride) {
        float av = w[t], bv = wq[t];
        float d = bv - av;
        sq += d * d;
        int bb = (__float_as_int(fmaf(bv, inv_a, MAGIC)) + qoff) & (NBINS - 1);
        u64 one = 1ull << ((bb & 7) << 3);
        clo += (bb < 8) ? one : 0ull; chi += (bb < 8) ? 0ull : one;
        int aa = (bb << 8) + tid;
        float2 tt = sv_pl[aa]; tt.x += av; tt.y += av * av; sv_pl[aa] = tt;
    }
    FLUSH_COUNTS();

    // wave-reduce sq
    for (int off = 32; off; off >>= 1) sq += __shfl_down(sq, off, 64);
    const int wave = tid >> 6, lane = tid & 63;
    if (lane == 0) sqpart[wave] = sq;

    // wave-reduce register counts into cred
    #pragma unroll
    for (int kk = 0; kk < NBINS; ++kk) {
        float v = cf[kk];
        for (int off = 32; off; off >>= 1) v += __shfl_down(v, off, 64);
        if (lane == 0) cred[kk][wave] = v;
    }
    __syncthreads();

    if (tid < NBINS)
        partial[tid * BLOCKS + blockIdx.x] =
            cred[tid][0] + cred[tid][1] + cred[tid][2] + cred[tid][3];

    // fold 256 sv columns -> 32 block partials; wave v handles cells 16+v, ...
    for (int c = 16 + wave; c < 48; c += 4) {
        const int bin = c & 15;
        float v = 0.0f;
        if (c < 32) {
            #pragma unroll
            for (int r = 0; r < TPB / 64; ++r)
                v += sv_pl[(bin << 8) + r * 64 + lane].x;
        } else {
            #pragma unroll
            for (int r = 0; r < TPB / 64; ++r)
                v += sv_pl[(bin << 8) + r * 64 + lane].y;
        }
        for (int off = 32; off; off >>= 1) v += __shfl_down(v, off, 64);
        if (lane == 0) partial[c * BLOCKS + blockIdx.x] = v;
    }
    if (tid == 0)
        partial[48 * BLOCKS + blockIdx.x] =
            sqpart[0] + sqpart[1] + sqpart[2] + sqpart[3];
}

__global__ __launch_bounds__(TPB) void binreg_final(
    const float* __restrict__ partial, float* __restrict__ out, long long n)
{
    __shared__ float cell[49];
    const int tid = threadIdx.x, wave = tid >> 6, lane = tid & 63;

    for (int c = wave; c < 49; c += 4) {
        float v0 = 0.0f, v1 = 0.0f, v2 = 0.0f, v3 = 0.0f;
        for (int r = lane; r < BLOCKS; r += 256) {
            v0 += partial[c * BLOCKS + r];
            v1 += partial[c * BLOCKS + r + 64];
            v2 += partial[c * BLOCKS + r + 128];
            v3 += partial[c * BLOCKS + r + 192];
        }
        float v = (v0 + v1) + (v2 + v3);
        for (int off = 32; off; off >>= 1) v += __shfl_down(v, off, 64);
        if (lane == 0) cell[c] = v;
    }
    __syncthreads();

    if (tid == 0) {
        float loss = cell[48] / (float)n;   // mean squared diff
        #pragma unroll
        for (int b = 0; b < NBINS; ++b) {
            float cnt = cell[b];
            float s   = cell[16 + b];
            float ss  = cell[32 + b];
            if (cnt > 1.0f)
                loss += (ss - s * s / cnt) / (cnt - 1.0f);  // unbiased var
        }
        out[0] = 0.1f * loss;   // LMBDA
    }
}

extern "C" void kernel_launch(void* const* d_in, const int* in_sizes, int n_in,
                              void* d_out, int out_size, void* d_ws, size_t ws_size,
                              hipStream_t stream)
{
    const float* w     = (const float*)d_in[0];
    const float* wq    = (const float*)d_in[1];
    const int*   nbit  = (const int*)d_in[2];
    const float* alpha = (const float*)d_in[3];
    float* out     = (float*)d_out;
    float* partial = (float*)d_ws;   // 49*BLOCKS floats, fully overwritten; no memset
    long long n = (long long)in_sizes[0];

    binreg_main<<<BLOCKS, TPB, 0, stream>>>(w, wq, alpha, nbit, partial, n);
    binreg_final<<<1, TPB, 0, stream>>>(partial, out, n);
}